// Round 5
// baseline (194.685 us; speedup 1.0000x reference)
//
#include <hip/hip_runtime.h>

constexpr int FD = 128;
constexpr int NBMAX = 512;   // max coarse buckets (rows/128); n<=65536
constexpr int CH1 = 2048;    // edges per binning block
constexpr int CAPQ = 1024;   // per-quarter-bucket (32 rows) edge capacity: mean 512, sigma~23

// ---- monotone float<->uint encoding for atomic max over floats ----
__device__ __forceinline__ unsigned fenc(float f) {
    unsigned u = __float_as_uint(f);
    return (u & 0x80000000u) ? ~u : (u | 0x80000000u);
}
__device__ __forceinline__ float fdec(unsigned e) {
    return (e & 0x80000000u) ? __uint_as_float(e & 0x7fffffffu)
                             : __uint_as_float(~e);
}

// RNE pack of two fp32 -> (lo=even feat, hi=odd feat) bf16 pair
__device__ __forceinline__ unsigned bpack(float x, float y) {
    unsigned ux = __float_as_uint(x); ux += 0x7FFFu + ((ux >> 16) & 1u);
    unsigned uy = __float_as_uint(y); uy += 0x7FFFu + ((uy >> 16) & 1u);
    return (ux >> 16) | (uy & 0xFFFF0000u);
}

// ---- W transpose + zero bucket histogram + init max slots (one dispatch) ----
__global__ __launch_bounds__(128) void initwt_kernel(const float* __restrict__ W,
                                                     float* __restrict__ Wt,
                                                     int* __restrict__ bhist,
                                                     unsigned* __restrict__ maxslot) {
    int j = blockIdx.x, k = threadIdx.x;
    Wt[(size_t)k * FD + j] = W[(size_t)j * FD + k];
    if (j == 0) {
        for (int i = k; i < NBMAX; i += 128) bhist[i] = 0;
        if (k < 2) maxslot[k] = 0x007FFFFFu;   // fenc(-inf)
    }
}

// ---- fused GEMM: Whb(bf16) = h @ W^T ; s1/s2 epilogue ----
__global__ __launch_bounds__(256) void gemm_kernel(const float* __restrict__ h,
                                                   const float* __restrict__ Wt,
                                                   const float* __restrict__ a,
                                                   unsigned* __restrict__ Whb,
                                                   float* __restrict__ s1,
                                                   float* __restrict__ s2, int n) {
    __shared__ float hs[FD * 36];  // h_t[k][r], row stride 36 dwords, XOR-swizzled groups
    int tid = threadIdx.x;
    int rbase = blockIdx.x * 32;

    {
        int rgrp = tid >> 5, k4 = tid & 31;
        float4 v[4];
#pragma unroll
        for (int i = 0; i < 4; ++i) {
            int gr = rbase + 4 * rgrp + i;
            v[i] = (gr < n) ? ((const float4*)h)[(size_t)gr * 32 + k4]
                            : make_float4(0.f, 0.f, 0.f, 0.f);
        }
#pragma unroll
        for (int kk = 0; kk < 4; ++kk) {
            int k = 4 * k4 + kk;
            float4 w;
            w.x = (&v[0].x)[kk]; w.y = (&v[1].x)[kk];
            w.z = (&v[2].x)[kk]; w.w = (&v[3].x)[kk];
            *(float4*)(hs + k * 36 + 4 * (rgrp ^ (k & 7))) = w;
        }
    }
    __syncthreads();

    int tc = tid & 31, tr = tid >> 5;
    float acc[4][4] = {};
    const float4* Wt4 = (const float4*)Wt;

#pragma unroll 4
    for (int k = 0; k < FD; ++k) {
        float4 w = Wt4[(size_t)k * 32 + tc];
        float4 hv = *(const float4*)(hs + k * 36 + 4 * (tr ^ (k & 7)));
#pragma unroll
        for (int i = 0; i < 4; ++i) {
            float hvi = (&hv.x)[i];
            acc[i][0] = fmaf(hvi, w.x, acc[i][0]);
            acc[i][1] = fmaf(hvi, w.y, acc[i][1]);
            acc[i][2] = fmaf(hvi, w.z, acc[i][2]);
            acc[i][3] = fmaf(hvi, w.w, acc[i][3]);
        }
    }

#pragma unroll
    for (int i = 0; i < 4; ++i) {
        int r = rbase + 4 * tr + i;
        if (r < n) {
            uint2 p;
            p.x = bpack(acc[i][0], acc[i][1]);
            p.y = bpack(acc[i][2], acc[i][3]);
            *(uint2*)(Whb + (size_t)r * 64 + 2 * tc) = p;
        }
    }

    float4 a1v = ((const float4*)a)[tc];
    float4 a2v = ((const float4*)a)[32 + tc];
    float p1[4], p2[4];
#pragma unroll
    for (int i = 0; i < 4; ++i) {
        p1[i] = acc[i][0] * a1v.x + acc[i][1] * a1v.y + acc[i][2] * a1v.z + acc[i][3] * a1v.w;
        p2[i] = acc[i][0] * a2v.x + acc[i][1] * a2v.y + acc[i][2] * a2v.z + acc[i][3] * a2v.w;
    }
#pragma unroll
    for (int d = 1; d < 32; d <<= 1) {
#pragma unroll
        for (int i = 0; i < 4; ++i) {
            p1[i] += __shfl_xor(p1[i], d, 64);
            p2[i] += __shfl_xor(p2[i], d, 64);
        }
    }
    if (tc == 0) {
#pragma unroll
        for (int i = 0; i < 4; ++i) {
            int r = rbase + 4 * tr + i;
            if (r < n) { s1[r] = p1[i]; s2[r] = p2[i]; }
        }
    }
}

// ---- grid-stride max-reduce of s1/s2 -> maxslot (2 atomics per block) ----
__global__ __launch_bounds__(256) void smax_kernel(const float* __restrict__ s1,
                                                   const float* __restrict__ s2,
                                                   unsigned* __restrict__ maxslot, int n) {
    __shared__ float m1s[4], m2s[4];
    int t = threadIdx.x, lane = t & 63, wid = t >> 6;
    float m1 = -3.0e38f, m2 = -3.0e38f;
    for (int i = blockIdx.x * 256 + t; i < n; i += gridDim.x * 256) {
        m1 = fmaxf(m1, s1[i]);
        m2 = fmaxf(m2, s2[i]);
    }
#pragma unroll
    for (int d = 1; d < 64; d <<= 1) {
        m1 = fmaxf(m1, __shfl_xor(m1, d, 64));
        m2 = fmaxf(m2, __shfl_xor(m2, d, 64));
    }
    if (lane == 0) { m1s[wid] = m1; m2s[wid] = m2; }
    __syncthreads();
    if (t == 0) {
        m1 = fmaxf(fmaxf(m1s[0], m1s[1]), fmaxf(m1s[2], m1s[3]));
        m2 = fmaxf(fmaxf(m2s[0], m2s[1]), fmaxf(m2s[2], m2s[3]));
        atomicMax(&maxslot[0], fenc(m1));
        atomicMax(&maxslot[1], fenc(m2));
    }
}

// ---- pass A: coarse bucket histogram (bucket = row >> 7), LDS-staged ----
__global__ __launch_bounds__(256) void bhist_kernel(const int* __restrict__ ei,
                                                    int* __restrict__ bhist,
                                                    int e_cnt, int nb) {
    __shared__ int h[NBMAX];
    int t = threadIdx.x;
    for (int i = t; i < NBMAX; i += 256) h[i] = 0;
    __syncthreads();
    int base = blockIdx.x * CH1;
    int m = min(CH1, e_cnt - base);
    for (int idx = t; idx < m; idx += 256) {
        int r = ei[base + idx];
        atomicAdd(&h[r >> 7], 1);
    }
    __syncthreads();
    for (int i = t; i < nb; i += 256)
        if (h[i]) atomicAdd(&bhist[i], h[i]);
}

// ---- scan bucket counts -> bstart / bcursor ----
__global__ __launch_bounds__(512) void bscan_kernel(const int* __restrict__ bhist,
                                                    int* __restrict__ bstart,
                                                    int* __restrict__ bcursor,
                                                    int nb, int e_cnt) {
    __shared__ int sc[512];
    int t = threadIdx.x;
    int v = (t < nb) ? bhist[t] : 0;
    sc[t] = v;
    __syncthreads();
    for (int off = 1; off < 512; off <<= 1) {
        int u = (t >= off) ? sc[t - off] : 0;
        __syncthreads();
        sc[t] += u;
        __syncthreads();
    }
    if (t < nb) {
        int ex = sc[t] - v;
        bstart[t] = ex;
        bcursor[t] = ex;
    }
    if (t == 0) bstart[nb] = e_cnt;
}

// ---- pass 1: LDS-staged binning into coarse buckets (contiguous writes) ----
__global__ __launch_bounds__(512) void bin_kernel(const int* __restrict__ ei,
                                                  int* __restrict__ bcursor,
                                                  unsigned* __restrict__ ebuf,
                                                  int e_cnt, int nb) {
    __shared__ int cnt[NBMAX];
    __shared__ int ex[NBMAX];
    __shared__ int gbase[NBMAX];
    __shared__ unsigned stage[CH1];
    int t = threadIdx.x;
    cnt[t] = 0;
    __syncthreads();
    int base = blockIdx.x * CH1;
    int m = min(CH1, e_cnt - base);

    unsigned pack[4];
    int rank[4], bkt[4];
    int nk = 0;
#pragma unroll
    for (int k = 0; k < 4; ++k) {
        int idx = t + k * 512;
        if (idx < m) {
            int e = base + idx;
            int r = ei[e];
            int c = ei[e_cnt + e];
            unsigned p = ((unsigned)r << 16) | (unsigned)c;
            int b = r >> 7;
            pack[nk] = p;
            bkt[nk] = b;
            rank[nk] = atomicAdd(&cnt[b], 1);
            ++nk;
        }
    }
    __syncthreads();
    int v = cnt[t];
    ex[t] = v;
    __syncthreads();
    for (int off = 1; off < 512; off <<= 1) {
        int u = (t >= off) ? ex[t - off] : 0;
        __syncthreads();
        ex[t] += u;
        __syncthreads();
    }
    int excl = ex[t] - v;
    if (t < nb && v > 0) gbase[t] = atomicAdd(&bcursor[t], v);
    __syncthreads();
    ex[t] = excl;
    __syncthreads();
    for (int k = 0; k < nk; ++k) stage[ex[bkt[k]] + rank[k]] = pack[k];
    __syncthreads();
    for (int s = t; s < m; s += 512) {
        unsigned p = stage[s];
        int b = p >> 23;
        ebuf[gbase[b] + (s - ex[b])] = p;
    }
}

// ---- merged scatter+aggregate: block = quarter-bucket (32 rows) ----
// LDS-sort the quarter's edges by local row, then per-node softmax + bf16
// gather-aggregate + elu. CSR never touches global memory.
__global__ __launch_bounds__(256) void agg_kernel(const unsigned* __restrict__ ebuf,
                                                  const int* __restrict__ bstart,
                                                  const float* __restrict__ s1,
                                                  const float* __restrict__ s2,
                                                  const unsigned* __restrict__ Whb,
                                                  const unsigned* __restrict__ maxslot,
                                                  float* __restrict__ out, int n) {
    __shared__ unsigned stage[CAPQ];   // 4 KB: this quarter's cols, row-sorted
    __shared__ float evs[CAPQ];        // 4 KB: exp(score - M) per edge
    __shared__ int cnt[32];
    __shared__ int exs[32];
    int b = blockIdx.x >> 2, q = blockIdx.x & 3;
    int t = threadIdx.x;
    int row0 = (b << 7) + (q << 5);
    int start = bstart[b];
    int m = bstart[b + 1] - start;

    // 1: histogram of this quarter's 32 local rows
    if (t < 32) cnt[t] = 0;
    __syncthreads();
    for (int i = t; i < m; i += 256) {
        int lr7 = (ebuf[start + i] >> 16) & 127;
        if ((lr7 >> 5) == q) atomicAdd(&cnt[lr7 & 31], 1);
    }
    __syncthreads();
    // 2: exclusive scan over 32 counters
    int v = (t < 32) ? cnt[t] : 0;
    if (t < 32) exs[t] = v;
    __syncthreads();
    for (int off = 1; off < 32; off <<= 1) {
        int u = (t < 32 && t >= off) ? exs[t - off] : 0;
        __syncthreads();
        if (t < 32) exs[t] += u;
        __syncthreads();
    }
    if (t < 32) { exs[t] -= v; cnt[t] = 0; }
    __syncthreads();
    // 3: rank + sort cols into stage (capacity-clamped; CAPQ is +22 sigma)
    for (int i = t; i < m; i += 256) {
        unsigned p = ebuf[start + i];
        int lr7 = (p >> 16) & 127;
        if ((lr7 >> 5) == q) {
            int lr = lr7 & 31;
            int rk = atomicAdd(&cnt[lr], 1);
            int pos = exs[lr] + rk;
            if (pos < CAPQ) stage[pos] = p & 0xFFFFu;
        }
    }
    __syncthreads();

    float M = fdec(maxslot[0]) + fdec(maxslot[1]);
    M = (M >= 0.f) ? M : 0.2f * M;   // leaky(upper bound) >= true max score
    int w = t >> 6, l = t & 63;
    int half = l >> 5, fl = l & 31;

    // 4: per-node softmax + aggregation (8 nodes per wave)
    for (int ni = w * 8; ni < w * 8 + 8; ++ni) {
        int node = row0 + ni;
        if (node >= n) break;
        int s0 = exs[ni], deg = min(cnt[ni], CAPQ - s0);
        float s1n = s1[node];

        // phase A: exp + sum, cache evs in LDS
        float psum = 0.f;
        for (int c0 = 0; c0 < deg; c0 += 64) {
            int idx = c0 + l;
            if (idx < deg) {
                int cc = (int)stage[s0 + idx];
                float sv = s1n + s2[cc];
                float le = (sv >= 0.f) ? sv : 0.2f * sv;
                float ev = expf(le - M);
                evs[s0 + idx] = ev;
                psum += ev;
            }
        }
#pragma unroll
        for (int d = 1; d < 64; d <<= 1) psum += __shfl_xor(psum, d, 64);
        float inv = 1.0f / (psum + 1e-10f);

        // phase B: 2 edges/iteration, uint2 (8B) gathers
        float4 acc = make_float4(0.f, 0.f, 0.f, 0.f);
        for (int j = half; j < deg; j += 2) {
            int cc = (int)stage[s0 + j];          // LDS broadcast per half
            float alpha = evs[s0 + j] * inv;      // LDS broadcast per half
            uint2 b2 = *(const uint2*)(Whb + (size_t)cc * 64 + 2 * fl);
            acc.x = fmaf(alpha, __uint_as_float(b2.x << 16), acc.x);
            acc.y = fmaf(alpha, __uint_as_float(b2.x & 0xFFFF0000u), acc.y);
            acc.z = fmaf(alpha, __uint_as_float(b2.y << 16), acc.z);
            acc.w = fmaf(alpha, __uint_as_float(b2.y & 0xFFFF0000u), acc.w);
        }
        acc.x += __shfl_xor(acc.x, 32, 64);
        acc.y += __shfl_xor(acc.y, 32, 64);
        acc.z += __shfl_xor(acc.z, 32, 64);
        acc.w += __shfl_xor(acc.w, 32, 64);
        if (half == 0) {
            float4 r;
            r.x = (acc.x > 0.f) ? acc.x : expm1f(acc.x);
            r.y = (acc.y > 0.f) ? acc.y : expm1f(acc.y);
            r.z = (acc.z > 0.f) ? acc.z : expm1f(acc.z);
            r.w = (acc.w > 0.f) ? acc.w : expm1f(acc.w);
            ((float4*)(out + (size_t)node * FD))[fl] = r;
        }
    }
}

extern "C" void kernel_launch(void* const* d_in, const int* in_sizes, int n_in,
                              void* d_out, int out_size, void* d_ws, size_t ws_size,
                              hipStream_t stream) {
    const float* h = (const float*)d_in[0];
    const int* ei  = (const int*)d_in[1];
    const float* W = (const float*)d_in[2];
    const float* a = (const float*)d_in[3];
    float* out = (float*)d_out;
    int n = in_sizes[0] / FD;   // 50000
    int e = in_sizes[1] / 2;    // 800000
    int nb = (n + 127) >> 7;    // coarse buckets (requires n <= 65536)

    char* ws = (char*)d_ws;
    size_t off = 0;
    auto alloc = [&](size_t bytes) -> void* {
        void* p = ws + off;
        off += bytes;
        off = (off + 255) & ~(size_t)255;
        return p;
    };
    unsigned* Whb     = (unsigned*)alloc((size_t)n * 64 * sizeof(unsigned));  // bf16 Wh
    float*    Wt      = (float*)alloc((size_t)FD * FD * sizeof(float));
    float*    s1      = (float*)alloc((size_t)n * sizeof(float));
    float*    s2      = (float*)alloc((size_t)n * sizeof(float));
    int*      bhist   = (int*)alloc((size_t)NBMAX * sizeof(int));
    int*      bstart  = (int*)alloc((size_t)(NBMAX + 1) * sizeof(int));
    int*      bcursor = (int*)alloc((size_t)NBMAX * sizeof(int));
    unsigned* ebuf    = (unsigned*)alloc((size_t)e * sizeof(unsigned));
    unsigned* maxslot = (unsigned*)alloc(2 * sizeof(unsigned));

    int eblocks = (e + CH1 - 1) / CH1;

    initwt_kernel<<<FD, FD, 0, stream>>>(W, Wt, bhist, maxslot);
    bhist_kernel<<<eblocks, 256, 0, stream>>>(ei, bhist, e, nb);
    gemm_kernel<<<(n + 31) / 32, 256, 0, stream>>>(h, Wt, a, Whb, s1, s2, n);
    smax_kernel<<<104, 256, 0, stream>>>(s1, s2, maxslot, n);
    bscan_kernel<<<1, 512, 0, stream>>>(bhist, bstart, bcursor, nb, e);
    bin_kernel<<<eblocks, 512, 0, stream>>>(ei, bcursor, ebuf, e, nb);
    agg_kernel<<<nb * 4, 256, 0, stream>>>(ebuf, bstart, s1, s2, Whb, maxslot, out, n);
}

// Round 6
// 182.676 us; speedup vs baseline: 1.0657x; 1.0657x over previous
//
#include <hip/hip_runtime.h>

constexpr int FD = 128;
constexpr int NBMAX = 512;   // max coarse buckets (rows/128); n<=65536
constexpr int CH1 = 2048;    // edges per binning block
constexpr int CAPB = 3072;   // per-bucket edge capacity (mean 2048, sigma~45 -> +22 sigma)

// ---- monotone float<->uint encoding for atomic max over floats ----
__device__ __forceinline__ unsigned fenc(float f) {
    unsigned u = __float_as_uint(f);
    return (u & 0x80000000u) ? ~u : (u | 0x80000000u);
}
__device__ __forceinline__ float fdec(unsigned e) {
    return (e & 0x80000000u) ? __uint_as_float(e & 0x7fffffffu)
                             : __uint_as_float(~e);
}

// RNE pack of two fp32 -> (lo=even feat, hi=odd feat) bf16 pair
__device__ __forceinline__ unsigned bpack(float x, float y) {
    unsigned ux = __float_as_uint(x); ux += 0x7FFFu + ((ux >> 16) & 1u);
    unsigned uy = __float_as_uint(y); uy += 0x7FFFu + ((uy >> 16) & 1u);
    return (ux >> 16) | (uy & 0xFFFF0000u);
}

// ---- W transpose + zero bucket histogram + init max slots (one dispatch) ----
__global__ __launch_bounds__(128) void initwt_kernel(const float* __restrict__ W,
                                                     float* __restrict__ Wt,
                                                     int* __restrict__ bhist,
                                                     unsigned* __restrict__ maxslot) {
    int j = blockIdx.x, k = threadIdx.x;
    Wt[(size_t)k * FD + j] = W[(size_t)j * FD + k];
    if (j == 0) {
        for (int i = k; i < NBMAX; i += 128) bhist[i] = 0;
        if (k < 2) maxslot[k] = 0x007FFFFFu;   // fenc(-inf)
    }
}

// ---- fused GEMM: Whb(bf16) = h @ W^T ; s1/s2 epilogue ----
__global__ __launch_bounds__(256) void gemm_kernel(const float* __restrict__ h,
                                                   const float* __restrict__ Wt,
                                                   const float* __restrict__ a,
                                                   unsigned* __restrict__ Whb,
                                                   float* __restrict__ s1,
                                                   float* __restrict__ s2, int n) {
    __shared__ float hs[FD * 36];  // h_t[k][r], row stride 36 dwords, XOR-swizzled groups
    int tid = threadIdx.x;
    int rbase = blockIdx.x * 32;

    {
        int rgrp = tid >> 5, k4 = tid & 31;
        float4 v[4];
#pragma unroll
        for (int i = 0; i < 4; ++i) {
            int gr = rbase + 4 * rgrp + i;
            v[i] = (gr < n) ? ((const float4*)h)[(size_t)gr * 32 + k4]
                            : make_float4(0.f, 0.f, 0.f, 0.f);
        }
#pragma unroll
        for (int kk = 0; kk < 4; ++kk) {
            int k = 4 * k4 + kk;
            float4 w;
            w.x = (&v[0].x)[kk]; w.y = (&v[1].x)[kk];
            w.z = (&v[2].x)[kk]; w.w = (&v[3].x)[kk];
            *(float4*)(hs + k * 36 + 4 * (rgrp ^ (k & 7))) = w;
        }
    }
    __syncthreads();

    int tc = tid & 31, tr = tid >> 5;
    float acc[4][4] = {};
    const float4* Wt4 = (const float4*)Wt;

#pragma unroll 4
    for (int k = 0; k < FD; ++k) {
        float4 w = Wt4[(size_t)k * 32 + tc];
        float4 hv = *(const float4*)(hs + k * 36 + 4 * (tr ^ (k & 7)));
#pragma unroll
        for (int i = 0; i < 4; ++i) {
            float hvi = (&hv.x)[i];
            acc[i][0] = fmaf(hvi, w.x, acc[i][0]);
            acc[i][1] = fmaf(hvi, w.y, acc[i][1]);
            acc[i][2] = fmaf(hvi, w.z, acc[i][2]);
            acc[i][3] = fmaf(hvi, w.w, acc[i][3]);
        }
    }

#pragma unroll
    for (int i = 0; i < 4; ++i) {
        int r = rbase + 4 * tr + i;
        if (r < n) {
            uint2 p;
            p.x = bpack(acc[i][0], acc[i][1]);
            p.y = bpack(acc[i][2], acc[i][3]);
            *(uint2*)(Whb + (size_t)r * 64 + 2 * tc) = p;
        }
    }

    float4 a1v = ((const float4*)a)[tc];
    float4 a2v = ((const float4*)a)[32 + tc];
    float p1[4], p2[4];
#pragma unroll
    for (int i = 0; i < 4; ++i) {
        p1[i] = acc[i][0] * a1v.x + acc[i][1] * a1v.y + acc[i][2] * a1v.z + acc[i][3] * a1v.w;
        p2[i] = acc[i][0] * a2v.x + acc[i][1] * a2v.y + acc[i][2] * a2v.z + acc[i][3] * a2v.w;
    }
#pragma unroll
    for (int d = 1; d < 32; d <<= 1) {
#pragma unroll
        for (int i = 0; i < 4; ++i) {
            p1[i] += __shfl_xor(p1[i], d, 64);
            p2[i] += __shfl_xor(p2[i], d, 64);
        }
    }
    if (tc == 0) {
#pragma unroll
        for (int i = 0; i < 4; ++i) {
            int r = rbase + 4 * tr + i;
            if (r < n) { s1[r] = p1[i]; s2[r] = p2[i]; }
        }
    }
}

// ---- grid-stride max-reduce of s1/s2 -> maxslot (2 atomics per block) ----
__global__ __launch_bounds__(256) void smax_kernel(const float* __restrict__ s1,
                                                   const float* __restrict__ s2,
                                                   unsigned* __restrict__ maxslot, int n) {
    __shared__ float m1s[4], m2s[4];
    int t = threadIdx.x, lane = t & 63, wid = t >> 6;
    float m1 = -3.0e38f, m2 = -3.0e38f;
    for (int i = blockIdx.x * 256 + t; i < n; i += gridDim.x * 256) {
        m1 = fmaxf(m1, s1[i]);
        m2 = fmaxf(m2, s2[i]);
    }
#pragma unroll
    for (int d = 1; d < 64; d <<= 1) {
        m1 = fmaxf(m1, __shfl_xor(m1, d, 64));
        m2 = fmaxf(m2, __shfl_xor(m2, d, 64));
    }
    if (lane == 0) { m1s[wid] = m1; m2s[wid] = m2; }
    __syncthreads();
    if (t == 0) {
        m1 = fmaxf(fmaxf(m1s[0], m1s[1]), fmaxf(m1s[2], m1s[3]));
        m2 = fmaxf(fmaxf(m2s[0], m2s[1]), fmaxf(m2s[2], m2s[3]));
        atomicMax(&maxslot[0], fenc(m1));
        atomicMax(&maxslot[1], fenc(m2));
    }
}

// ---- pass A: coarse bucket histogram (bucket = row >> 7), LDS-staged ----
__global__ __launch_bounds__(256) void bhist_kernel(const int* __restrict__ ei,
                                                    int* __restrict__ bhist,
                                                    int e_cnt, int nb) {
    __shared__ int h[NBMAX];
    int t = threadIdx.x;
    for (int i = t; i < NBMAX; i += 256) h[i] = 0;
    __syncthreads();
    int base = blockIdx.x * CH1;
    int m = min(CH1, e_cnt - base);
    for (int idx = t; idx < m; idx += 256) {
        int r = ei[base + idx];
        atomicAdd(&h[r >> 7], 1);
    }
    __syncthreads();
    for (int i = t; i < nb; i += 256)
        if (h[i]) atomicAdd(&bhist[i], h[i]);
}

// ---- scan bucket counts -> bstart / bcursor ----
__global__ __launch_bounds__(512) void bscan_kernel(const int* __restrict__ bhist,
                                                    int* __restrict__ bstart,
                                                    int* __restrict__ bcursor,
                                                    int nb, int e_cnt) {
    __shared__ int sc[512];
    int t = threadIdx.x;
    int v = (t < nb) ? bhist[t] : 0;
    sc[t] = v;
    __syncthreads();
    for (int off = 1; off < 512; off <<= 1) {
        int u = (t >= off) ? sc[t - off] : 0;
        __syncthreads();
        sc[t] += u;
        __syncthreads();
    }
    if (t < nb) {
        int ex = sc[t] - v;
        bstart[t] = ex;
        bcursor[t] = ex;
    }
    if (t == 0) bstart[nb] = e_cnt;
}

// ---- pass 1: LDS-staged binning into coarse buckets (contiguous writes) ----
__global__ __launch_bounds__(512) void bin_kernel(const int* __restrict__ ei,
                                                  int* __restrict__ bcursor,
                                                  unsigned* __restrict__ ebuf,
                                                  int e_cnt, int nb) {
    __shared__ int cnt[NBMAX];
    __shared__ int ex[NBMAX];
    __shared__ int gbase[NBMAX];
    __shared__ unsigned stage[CH1];
    int t = threadIdx.x;
    cnt[t] = 0;
    __syncthreads();
    int base = blockIdx.x * CH1;
    int m = min(CH1, e_cnt - base);

    unsigned pack[4];
    int rank[4], bkt[4];
    int nk = 0;
#pragma unroll
    for (int k = 0; k < 4; ++k) {
        int idx = t + k * 512;
        if (idx < m) {
            int e = base + idx;
            int r = ei[e];
            int c = ei[e_cnt + e];
            unsigned p = ((unsigned)r << 16) | (unsigned)c;
            int b = r >> 7;
            pack[nk] = p;
            bkt[nk] = b;
            rank[nk] = atomicAdd(&cnt[b], 1);
            ++nk;
        }
    }
    __syncthreads();
    int v = cnt[t];
    ex[t] = v;
    __syncthreads();
    for (int off = 1; off < 512; off <<= 1) {
        int u = (t >= off) ? ex[t - off] : 0;
        __syncthreads();
        ex[t] += u;
        __syncthreads();
    }
    int excl = ex[t] - v;
    if (t < nb && v > 0) gbase[t] = atomicAdd(&bcursor[t], v);
    __syncthreads();
    ex[t] = excl;
    __syncthreads();
    for (int k = 0; k < nk; ++k) stage[ex[bkt[k]] + rank[k]] = pack[k];
    __syncthreads();
    for (int s = t; s < m; s += 512) {
        unsigned p = stage[s];
        int b = p >> 23;
        ebuf[gbase[b] + (s - ex[b])] = p;
    }
}

// ---- merged sort+softmax+aggregate: block = one full bucket (128 rows, 1024 thr) ----
__global__ __launch_bounds__(1024) void agg_kernel(const unsigned* __restrict__ ebuf,
                                                   const int* __restrict__ bstart,
                                                   const float* __restrict__ s1,
                                                   const float* __restrict__ s2,
                                                   const unsigned* __restrict__ Whb,
                                                   const unsigned* __restrict__ maxslot,
                                                   float* __restrict__ out, int n) {
    __shared__ unsigned stage[CAPB];   // 12 KB: row-sorted packed (row|col)
    __shared__ float evs[CAPB];        // 12 KB: exp -> normalized alpha
    __shared__ int cnt[128];
    __shared__ int exs[128];
    __shared__ float invs[128];
    __shared__ float s1l[128];
    int b = blockIdx.x;
    int t = threadIdx.x;
    int row0 = b << 7;
    int start = bstart[b];
    int m = min(bstart[b + 1] - start, CAPB);

    if (t < 128) {
        cnt[t] = 0;
        int gr = row0 + t;
        s1l[t] = (gr < n) ? s1[gr] : 0.f;
    }
    __syncthreads();
    // 1: histogram of 128 local rows (single pass over own segment)
    for (int i = t; i < m; i += 1024)
        atomicAdd(&cnt[(ebuf[start + i] >> 16) & 127], 1);
    __syncthreads();
    // 2: exclusive scan over 128 counters
    int v = (t < 128) ? cnt[t] : 0;
    if (t < 128) exs[t] = v;
    __syncthreads();
    for (int off = 1; off < 128; off <<= 1) {
        int u = (t < 128 && t >= off) ? exs[t - off] : 0;
        __syncthreads();
        if (t < 128) exs[t] += u;
        __syncthreads();
    }
    if (t < 128) { exs[t] -= v; cnt[t] = 0; }
    __syncthreads();
    // 3: row-sort packed edges into LDS
    for (int i = t; i < m; i += 1024) {
        unsigned p = ebuf[start + i];
        int lr = (p >> 16) & 127;
        int rk = atomicAdd(&cnt[lr], 1);
        stage[exs[lr] + rk] = p;
    }
    __syncthreads();

    float M = fdec(maxslot[0]) + fdec(maxslot[1]);
    M = (M >= 0.f) ? M : 0.2f * M;   // leaky(upper bound) >= true max score

    // 4: flat exp pass (full lane utilization)
    for (int i = t; i < m; i += 1024) {
        unsigned p = stage[i];
        float sv = s1l[(p >> 16) & 127] + s2[p & 0xFFFFu];
        float le = (sv >= 0.f) ? sv : 0.2f * sv;
        evs[i] = expf(le - M);
    }
    __syncthreads();
    // 5: per-node denominators (serial ~deg=16 LDS reads; 2-way bank alias = free)
    if (t < 128) {
        int s0 = exs[t], d = cnt[t];
        float s = 0.f;
        for (int k = 0; k < d; ++k) s += evs[s0 + k];
        invs[t] = 1.0f / (s + 1e-10f);
    }
    __syncthreads();
    // 6: normalize alphas flat
    for (int i = t; i < m; i += 1024)
        evs[i] *= invs[(stage[i] >> 16) & 127];
    __syncthreads();

    // 7: aggregation — wave w -> 8 nodes; half-wave per edge; 2-deep load pipeline
    int w = t >> 6, l = t & 63, half = l >> 5, fl = l & 31;
    for (int ni = (w << 3); ni < (w << 3) + 8; ++ni) {
        int node = row0 + ni;
        if (node >= n) break;
        int s0 = exs[ni], deg = cnt[ni];
        float4 acc = make_float4(0.f, 0.f, 0.f, 0.f);
        int j = half;
        for (; j + 2 < deg; j += 4) {
            unsigned c0 = stage[s0 + j] & 0xFFFFu;
            unsigned c1 = stage[s0 + j + 2] & 0xFFFFu;
            float a0 = evs[s0 + j], a1 = evs[s0 + j + 2];
            uint2 b0 = *(const uint2*)(Whb + (size_t)c0 * 64 + 2 * fl);
            uint2 b1 = *(const uint2*)(Whb + (size_t)c1 * 64 + 2 * fl);
            acc.x = fmaf(a0, __uint_as_float(b0.x << 16), acc.x);
            acc.y = fmaf(a0, __uint_as_float(b0.x & 0xFFFF0000u), acc.y);
            acc.z = fmaf(a0, __uint_as_float(b0.y << 16), acc.z);
            acc.w = fmaf(a0, __uint_as_float(b0.y & 0xFFFF0000u), acc.w);
            acc.x = fmaf(a1, __uint_as_float(b1.x << 16), acc.x);
            acc.y = fmaf(a1, __uint_as_float(b1.x & 0xFFFF0000u), acc.y);
            acc.z = fmaf(a1, __uint_as_float(b1.y << 16), acc.z);
            acc.w = fmaf(a1, __uint_as_float(b1.y & 0xFFFF0000u), acc.w);
        }
        if (j < deg) {
            unsigned c0 = stage[s0 + j] & 0xFFFFu;
            float a0 = evs[s0 + j];
            uint2 b0 = *(const uint2*)(Whb + (size_t)c0 * 64 + 2 * fl);
            acc.x = fmaf(a0, __uint_as_float(b0.x << 16), acc.x);
            acc.y = fmaf(a0, __uint_as_float(b0.x & 0xFFFF0000u), acc.y);
            acc.z = fmaf(a0, __uint_as_float(b0.y << 16), acc.z);
            acc.w = fmaf(a0, __uint_as_float(b0.y & 0xFFFF0000u), acc.w);
        }
        acc.x += __shfl_xor(acc.x, 32, 64);
        acc.y += __shfl_xor(acc.y, 32, 64);
        acc.z += __shfl_xor(acc.z, 32, 64);
        acc.w += __shfl_xor(acc.w, 32, 64);
        if (half == 0) {
            float4 r;
            r.x = (acc.x > 0.f) ? acc.x : expm1f(acc.x);
            r.y = (acc.y > 0.f) ? acc.y : expm1f(acc.y);
            r.z = (acc.z > 0.f) ? acc.z : expm1f(acc.z);
            r.w = (acc.w > 0.f) ? acc.w : expm1f(acc.w);
            ((float4*)(out + (size_t)node * FD))[fl] = r;
        }
    }
}

extern "C" void kernel_launch(void* const* d_in, const int* in_sizes, int n_in,
                              void* d_out, int out_size, void* d_ws, size_t ws_size,
                              hipStream_t stream) {
    const float* h = (const float*)d_in[0];
    const int* ei  = (const int*)d_in[1];
    const float* W = (const float*)d_in[2];
    const float* a = (const float*)d_in[3];
    float* out = (float*)d_out;
    int n = in_sizes[0] / FD;   // 50000
    int e = in_sizes[1] / 2;    // 800000
    int nb = (n + 127) >> 7;    // coarse buckets (requires n <= 65536)

    char* ws = (char*)d_ws;
    size_t off = 0;
    auto alloc = [&](size_t bytes) -> void* {
        void* p = ws + off;
        off += bytes;
        off = (off + 255) & ~(size_t)255;
        return p;
    };
    unsigned* Whb     = (unsigned*)alloc((size_t)n * 64 * sizeof(unsigned));  // bf16 Wh
    float*    Wt      = (float*)alloc((size_t)FD * FD * sizeof(float));
    float*    s1      = (float*)alloc((size_t)n * sizeof(float));
    float*    s2      = (float*)alloc((size_t)n * sizeof(float));
    int*      bhist   = (int*)alloc((size_t)NBMAX * sizeof(int));
    int*      bstart  = (int*)alloc((size_t)(NBMAX + 1) * sizeof(int));
    int*      bcursor = (int*)alloc((size_t)NBMAX * sizeof(int));
    unsigned* ebuf    = (unsigned*)alloc((size_t)e * sizeof(unsigned));
    unsigned* maxslot = (unsigned*)alloc(2 * sizeof(unsigned));

    int eblocks = (e + CH1 - 1) / CH1;

    initwt_kernel<<<FD, FD, 0, stream>>>(W, Wt, bhist, maxslot);
    bhist_kernel<<<eblocks, 256, 0, stream>>>(ei, bhist, e, nb);
    gemm_kernel<<<(n + 31) / 32, 256, 0, stream>>>(h, Wt, a, Whb, s1, s2, n);
    smax_kernel<<<104, 256, 0, stream>>>(s1, s2, maxslot, n);
    bscan_kernel<<<1, 512, 0, stream>>>(bhist, bstart, bcursor, nb, e);
    bin_kernel<<<eblocks, 512, 0, stream>>>(ei, bcursor, ebuf, e, nb);
    agg_kernel<<<nb, 1024, 0, stream>>>(ebuf, bstart, s1, s2, Whb, maxslot, out, n);
}